// Round 1
// baseline (414.541 us; speedup 1.0000x reference)
//
#include <hip/hip_runtime.h>
#include <math.h>

// Problem constants (from reference):
// B=2048, C=1, H=W=128, TARGET_H=TARGET_W=70, SAVE=CUT=64, CX=CY=64.0
// Outputs (flat concat, fp32):
//   out0 target       : (2048,1,64,64)    = image*mask cropped [32:96,32:96]
//   out1 target_cut   : (2048,1,64,64)    = min(2*image,1) cropped [32:96,32:96]
//   out2 target_scene : (2048,1,128,128)  = image * (mask==0)
//   out3 target_raw   : (2048,1,128,128)  = image
//
// Mask is analytic: rotated-rectangle test per pixel, no gather needed.
// Numerics: fp32 ops via __f*_rn to match numpy op-for-op (no FMA contraction);
// per-image cos/sin computed in double then rounded -> correctly-rounded fp32.

#define NB 2048

__global__ __launch_bounds__(256) void kd_rotmask_kernel(
    const float* __restrict__ image,
    const float* __restrict__ azim,
    const float* __restrict__ alpha,
    float* __restrict__ out)
{
    const int b   = blockIdx.y;                       // image index, uniform per block
    const int tid = blockIdx.x * 256 + threadIdx.x;   // 0..4095 : float4 index in image

    __shared__ float s_cs, s_sn, s_xd, s_xu, s_yd, s_yu;
    if (threadIdx.x == 0) {
        // a = deg2rad(-azimuth[b]) in fp32 exactly as numpy: (-az) * float32(pi/180)
        float a = __fmul_rn(-azim[b], 0.017453292519943295f);
        double ad = (double)a;
        s_cs = (float)cos(ad);   // correctly-rounded fp32 trig
        s_sn = (float)sin(ad);
        // x_up = round(CX + a0*35), round-half-even (jnp.round) == rintf
        s_xu = rintf(__fadd_rn(64.0f, __fmul_rn(alpha[0], 35.0f)));
        s_xd = rintf(__fsub_rn(64.0f, __fmul_rn(alpha[1], 35.0f)));
        s_yu = rintf(__fadd_rn(64.0f, __fmul_rn(alpha[2], 35.0f)));
        s_yd = rintf(__fsub_rn(64.0f, __fmul_rn(alpha[3], 35.0f)));
    }
    __syncthreads();
    const float cs = s_cs, sn = s_sn;
    const float xd = s_xd, xu = s_xu, yd = s_yd, yu = s_yu;

    const int row  = tid >> 5;        // 0..127
    const int c4   = tid & 31;        // float4-chunk within row
    const int col0 = c4 << 2;         // first pixel column of this chunk

    const float4* img4 = (const float4*)image + (size_t)b * 4096 + tid;
    const float4 v = *img4;
    const float px[4] = {v.x, v.y, v.z, v.w};

    const float Yf = (float)row - 63.5f;   // exact in fp32
    float tgt[4], scn[4];
    #pragma unroll
    for (int j = 0; j < 4; ++j) {
        const float Xf = (float)(col0 + j) - 63.5f;   // exact
        // xin = cos*X + sin*Y ; yin = (-sin)*X + cos*Y   (numpy op order, no fma)
        const float xin = __fadd_rn(__fmul_rn(cs, Xf), __fmul_rn(sn, Yf));
        const float yin = __fadd_rn(__fmul_rn(-sn, Xf), __fmul_rn(cs, Yf));
        const float colf = floorf(__fadd_rn(__fadd_rn(xin, 63.5f), 0.5f));
        const float rowf = floorf(__fadd_rn(__fadd_rn(yin, 63.5f), 0.5f));
        const bool valid = (colf >= 0.0f) && (colf < 128.0f) &&
                           (rowf >= 0.0f) && (rowf < 128.0f);
        // clip (reference clips then indexes; validity zeroes the result anyway)
        const float rc = fminf(fmaxf(rowf, 0.0f), 127.0f);
        const float cc = fminf(fmaxf(colf, 0.0f), 127.0f);
        const bool m = valid && (rc >= xd) && (rc < xu) && (cc >= yd) && (cc < yu);
        tgt[j] = m ? px[j] : 0.0f;   // image * mask
        scn[j] = m ? 0.0f : px[j];   // image * (mask==0)
    }

    // float4-unit offsets in concatenated output:
    //   out0 @ 0            (2048*1024 float4)
    //   out1 @ 2097152      (2048*1024)
    //   out2 @ 4194304      (2048*4096)
    //   out3 @ 12582912     (2048*4096)
    float4* out4 = (float4*)out;
    const size_t full_idx = (size_t)b * 4096 + tid;
    out4[4194304u + full_idx]  = make_float4(scn[0], scn[1], scn[2], scn[3]);
    out4[12582912u + full_idx] = v;

    // crop region: rows 32..95, cols 32..95  -> c4 chunks 8..23 (16B aligned)
    if (row >= 32 && row < 96 && c4 >= 8 && c4 < 24) {
        const size_t ti = (size_t)b * 1024 + (size_t)(row - 32) * 16 + (c4 - 8);
        out4[ti] = make_float4(tgt[0], tgt[1], tgt[2], tgt[3]);
        float cut[4];
        #pragma unroll
        for (int j = 0; j < 4; ++j) {
            const float e = __fmul_rn(px[j], 2.0f);     // exact
            cut[j] = (e >= 1.0f) ? 1.0f : e;            // image_eq
        }
        out4[2097152u + ti] = make_float4(cut[0], cut[1], cut[2], cut[3]);
    }
}

extern "C" void kernel_launch(void* const* d_in, const int* in_sizes, int n_in,
                              void* d_out, int out_size, void* d_ws, size_t ws_size,
                              hipStream_t stream) {
    const float* image = (const float*)d_in[0];
    const float* azim  = (const float*)d_in[1];
    const float* alpha = (const float*)d_in[2];
    float* out = (float*)d_out;

    dim3 grid(16, NB);   // 16 blocks x 256 threads = 4096 float4 / image
    dim3 block(256);
    hipLaunchKernelGGL(kd_rotmask_kernel, grid, block, 0, stream,
                       image, azim, alpha, out);
}